// Round 9
// baseline (314.592 us; speedup 1.0000x reference)
//
#include <hip/hip_runtime.h>
#include <math.h>

// Problem constants
#define NTOK 4096
#define PCH  128
#define ICH  256
#define OCH  128
#define NB   2
#define SCALEF 0.08838834764831845f   // 1/sqrt(128)

typedef __bf16 bf16_t;
typedef __attribute__((ext_vector_type(8))) __bf16 bf16x8;
typedef __attribute__((ext_vector_type(4))) __bf16 bf16x4;
typedef __attribute__((ext_vector_type(4))) float floatx4;

#define LDK  136   // padded row length (bf16) for k=128 tiles (row shift 4 dw -> <=2-way per m136)
#define LDJ2 136   // padded row length (bf16) for j=128 Es tiles

// ---------------------------------------------------------------------------
// K-1: zero fus (8 MB) + zsum buffers (64 KB) — contiguous at ws start.
// ---------------------------------------------------------------------------
__global__ __launch_bounds__(256) void zero_kernel(float4* __restrict__ p)
{
    p[(size_t)blockIdx.x * 256 + threadIdx.x] = float4{0.f, 0.f, 0.f, 0.f};
}

// ---------------------------------------------------------------------------
// K0: pack pf -> pfC (bf16 channel-major) + pfT (bf16 token-major)
// ---------------------------------------------------------------------------
__global__ __launch_bounds__(256) void pack_pf(const float* __restrict__ pf,
                                               bf16_t* __restrict__ pfC,
                                               bf16_t* __restrict__ pfT)
{
    __shared__ float Ls[64][65];
    const int t = threadIdx.x;
    const int n0 = blockIdx.x * 64, d0 = blockIdx.y * 64, b = blockIdx.z;
    const float* src = pf + ((size_t)(b * PCH + d0)) * NTOK + n0;
#pragma unroll
    for (int p = 0; p < 4; p++) {
        int d = p * 16 + (t >> 4), c = t & 15;
        float4 v = *(const float4*)&src[d * NTOK + c * 4];
        Ls[d][c * 4 + 0] = v.x; Ls[d][c * 4 + 1] = v.y;
        Ls[d][c * 4 + 2] = v.z; Ls[d][c * 4 + 3] = v.w;
        bf16x4 o = { (bf16_t)v.x, (bf16_t)v.y, (bf16_t)v.z, (bf16_t)v.w };
        *(bf16x4*)&pfC[((size_t)(b * PCH + d0 + d)) * NTOK + n0 + c * 4] = o;
    }
    __syncthreads();
#pragma unroll
    for (int p = 0; p < 2; p++) {
        int n = p * 32 + (t >> 3), c = t & 7;
        bf16x8 o;
#pragma unroll
        for (int k = 0; k < 8; k++) o[k] = (bf16_t)Ls[c * 8 + k][n];
        *(bf16x8*)&pfT[((size_t)(b * NTOK + n0 + n)) * PCH + d0 + c * 8] = o;
    }
}

// ---------------------------------------------------------------------------
// K1: fc2 — ri[b][p][n] = sum_c img[b][c][n]*w[p][c] + bias[p]
// ---------------------------------------------------------------------------
__global__ __launch_bounds__(256) void fc2_kernel(const float* __restrict__ img,
                                                  const float* __restrict__ w,
                                                  const float* __restrict__ bias,
                                                  bf16_t* __restrict__ riC,
                                                  bf16_t* __restrict__ riT)
{
    const int b = blockIdx.z, t = threadIdx.x;
    const int n = blockIdx.x * 64 + (t & 63);
    const int pbase = blockIdx.y * 32 + (t >> 6) * 8;   // wave-uniform
    const float* imgb = img + (size_t)b * ICH * NTOK + n;

    float acc[8];
#pragma unroll
    for (int pp = 0; pp < 8; pp++) acc[pp] = bias[pbase + pp];

    for (int c = 0; c < ICH; c += 4) {
        float v0 = imgb[(c + 0) * NTOK];
        float v1 = imgb[(c + 1) * NTOK];
        float v2 = imgb[(c + 2) * NTOK];
        float v3 = imgb[(c + 3) * NTOK];
#pragma unroll
        for (int pp = 0; pp < 8; pp++) {
            float4 wv = *(const float4*)&w[(pbase + pp) * ICH + c];
            acc[pp] += wv.x * v0 + wv.y * v1 + wv.z * v2 + wv.w * v3;
        }
    }

#pragma unroll
    for (int pp = 0; pp < 8; pp++)
        riC[((size_t)(b * PCH + pbase + pp)) * NTOK + n] = (bf16_t)acc[pp];
    bf16x8 tv;
#pragma unroll
    for (int pp = 0; pp < 8; pp++) tv[pp] = (bf16_t)acc[pp];
    *(bf16x8*)&riT[((size_t)(b * NTOK + n)) * PCH + pbase] = tv;
}

// ---------------------------------------------------------------------------
// K2: stats v5 — one pass over E = exp(scale * pf_i . ri_j), both reductions:
//   zr[i] += sum_j E[i,j],  zc[j] += sum_i E[i,j]
// Direct-global B fragments (attn-proven pattern) + raw s_barrier per iter as
// PACING only (no waitcnt drain -> prefetch stays in flight). zcol batched in
// a 4 KB LDS accumulator (each slot written exactly once), one coalesced
// atomic flush at the end. LDS 21.5 KB.
// ---------------------------------------------------------------------------
__global__ __launch_bounds__(256, 4) void stats_mfma(const bf16_t* __restrict__ pfT,
                                                     const bf16_t* __restrict__ riT,
                                                     float* __restrict__ zr,
                                                     float* __restrict__ zc)
{
    __shared__ bf16_t As[64 * LDK];
    __shared__ float zacc[1024];
    const int b = blockIdx.y, t = threadIdx.x;
    const int js = blockIdx.z;
    const bf16_t* At = pfT + (size_t)b * NTOK * PCH;
    const bf16_t* Bt = riT + (size_t)b * NTOK * PCH;
    float* zrow = zr + (size_t)b * NTOK;
    float* zcol = zc + (size_t)b * NTOK;
    const int lane = t & 63, w = t >> 6, tx = lane & 15, q = lane >> 4;
    const int i0 = blockIdx.x * 64;
    const int jbase = js * 1024;
    const int sr = t >> 4, sc = t & 15;
    const bf16_t* Brow = Bt + (size_t)(jbase + w * 16 + tx) * PCH;

    // prefetch first B fragments, then stage A band
    bf16x8 bcur[4];
#pragma unroll
    for (int s = 0; s < 4; s++)
        bcur[s] = *(const bf16x8*)&Brow[s * 32 + q * 8];
#pragma unroll
    for (int p = 0; p < 4; p++) {
        int i = p * 16 + sr;
        *(uint4*)&As[i * LDK + sc * 8] = *(const uint4*)&At[((size_t)(i0 + i)) * PCH + sc * 8];
    }
    __syncthreads();
    bf16x8 af[4][4];
#pragma unroll
    for (int mt = 0; mt < 4; mt++)
#pragma unroll
        for (int s = 0; s < 4; s++)
            af[mt][s] = *(bf16x8*)&As[(mt * 16 + tx) * LDK + s * 32 + q * 8];

    float racc[4] = {0.f, 0.f, 0.f, 0.f};
    for (int jt = 0; jt < 16; jt++) {
        __builtin_amdgcn_s_barrier();            // pacing only (keeps waves/blocks
                                                 // in L2-temporal lockstep)
        // swapped GEMM: lane holds E^T tile: j = jbase+jt*64+w*16+q*4+r, i = i0+mt*16+tx
        floatx4 sacc[4];
#pragma unroll
        for (int mt = 0; mt < 4; mt++) {
            sacc[mt] = (floatx4){0.f, 0.f, 0.f, 0.f};
#pragma unroll
            for (int s = 0; s < 4; s++)
                sacc[mt] = __builtin_amdgcn_mfma_f32_16x16x32_bf16(bcur[s], af[mt][s], sacc[mt], 0, 0, 0);
        }
        if (jt < 15) {                           // reload B frags for next tile
            const bf16_t* bn = Brow + (size_t)(jt + 1) * 64 * PCH;
#pragma unroll
            for (int s = 0; s < 4; s++)
                bcur[s] = *(const bf16x8*)&bn[s * 32 + q * 8];
        }

        float ctmp[4] = {0.f, 0.f, 0.f, 0.f};
#pragma unroll
        for (int mt = 0; mt < 4; mt++)
#pragma unroll
            for (int r = 0; r < 4; r++) {
                float e = __expf(sacc[mt][r] * SCALEF);
                racc[mt] += e;                   // row partial (over j)
                ctmp[r]  += e;                   // col partial (over i in-lane)
            }
        // col sums: reduce the 16 tx lanes, store to LDS slot (written once)
#pragma unroll
        for (int r = 0; r < 4; r++) {
            float v = ctmp[r];
            v += __shfl_xor(v, 1); v += __shfl_xor(v, 2);
            v += __shfl_xor(v, 4); v += __shfl_xor(v, 8);
            if (tx == 0) zacc[jt * 64 + w * 16 + q * 4 + r] = v;
        }
    }
    // row sums: combine quads then one atomic per i per wave
#pragma unroll
    for (int mt = 0; mt < 4; mt++) {
        float v = racc[mt];
        v += __shfl_xor(v, 16);
        v += __shfl_xor(v, 32);
        if (q == 0) atomicAdd(&zrow[i0 + mt * 16 + tx], v);
    }
    __syncthreads();                             // zacc visible to all
    // col sums: coalesced flush, 4 atomics/thread
#pragma unroll
    for (int k = 0; k < 4; k++)
        atomicAdd(&zcol[jbase + k * 256 + t], zacc[k * 256 + t]);
}

// ---------------------------------------------------------------------------
// K3: attn v4 — fus[i][d] += sum_{j in quarter} exp(scale*A_i.B_j)/zsum[j]*A_j[d]
// j-tile widened to 128: 64 MFMA per single barrier (8 iterations). Direct
// global B/V-frag prefetch, swapped GEMM1 (b64 Es writes), Es dbuf [64][136].
// LDS 52.2 KB -> 3 blocks/CU.
// ---------------------------------------------------------------------------
__global__ __launch_bounds__(256, 3) void attn_mfma(const bf16_t* __restrict__ pfT,
                                                    const bf16_t* __restrict__ riT,
                                                    const bf16_t* __restrict__ pfC,
                                                    const bf16_t* __restrict__ riC,
                                                    const float* __restrict__ zrsum,
                                                    const float* __restrict__ zcsum,
                                                    float* __restrict__ fus)
{
    __shared__ bf16_t As[64 * LDK];
    __shared__ bf16_t Es[2][64 * LDJ2];
    const int b = blockIdx.y, t = threadIdx.x;
    const int mode = blockIdx.z >> 2, js = blockIdx.z & 3;
    const bf16_t* At = (mode == 0 ? pfT : riT) + (size_t)b * NTOK * PCH;
    const bf16_t* Bt = (mode == 0 ? riT : pfT) + (size_t)b * NTOK * PCH;
    const bf16_t* Vc = (mode == 0 ? pfC : riC) + (size_t)b * PCH * NTOK;
    const float* wsum = (mode == 0 ? zcsum : zrsum) + (size_t)b * NTOK;
    const int lane = t & 63, w = t >> 6, tx = lane & 15, q = lane >> 4;
    const int i0 = blockIdx.x * 64;
    const int jbase = js * 1024;
    const int sr = t >> 4, sc = t & 15;
    const bf16_t* Brow0 = Bt + (size_t)(jbase + w * 32 + tx) * PCH;       // g=0 rows
    const bf16_t* Brow1 = Bt + (size_t)(jbase + w * 32 + 16 + tx) * PCH;  // g=1 rows

    // prefetch B frags (jt=0), V frags (jt=0), wsum quads (jt=0)
    bf16x8 bcur[2][4];
#pragma unroll
    for (int s = 0; s < 4; s++) {
        bcur[0][s] = *(const bf16x8*)&Brow0[s * 32 + q * 8];
        bcur[1][s] = *(const bf16x8*)&Brow1[s * 32 + q * 8];
    }
    bf16x8 vcur[2][4];
#pragma unroll
    for (int nt = 0; nt < 2; nt++)
#pragma unroll
        for (int s = 0; s < 4; s++)
            vcur[nt][s] = *(const bf16x8*)&Vc[((size_t)(w * 32 + nt * 16 + tx)) * NTOK + jbase + s * 32 + q * 8];
    float4 wv0 = *(const float4*)&wsum[jbase + w * 32 + q * 4];
    float4 wv1 = *(const float4*)&wsum[jbase + w * 32 + 16 + q * 4];
    float4 wr0 = {1.f / wv0.x, 1.f / wv0.y, 1.f / wv0.z, 1.f / wv0.w};
    float4 wr1 = {1.f / wv1.x, 1.f / wv1.y, 1.f / wv1.z, 1.f / wv1.w};

#pragma unroll
    for (int p = 0; p < 4; p++) {
        int i = p * 16 + sr;
        *(uint4*)&As[i * LDK + sc * 8] = *(const uint4*)&At[((size_t)(i0 + i)) * PCH + sc * 8];
    }
    __syncthreads();
    bf16x8 af[4][4];
#pragma unroll
    for (int mt = 0; mt < 4; mt++)
#pragma unroll
        for (int s = 0; s < 4; s++)
            af[mt][s] = *(bf16x8*)&As[(mt * 16 + tx) * LDK + s * 32 + q * 8];

    floatx4 outacc[4][2];
#pragma unroll
    for (int mt = 0; mt < 4; mt++)
#pragma unroll
        for (int nt = 0; nt < 2; nt++)
            outacc[mt][nt] = (floatx4){0.f, 0.f, 0.f, 0.f};

    for (int jt = 0; jt < 8; jt++) {
        const int cur = jt & 1;
        const int j0 = jbase + jt * 128;

        // ---- GEMM1 (swapped): lane holds S^T: j = j0+w*32+g*16+q*4+r, i = i0+mt*16+tx
        floatx4 sacc[2][4];
#pragma unroll
        for (int g = 0; g < 2; g++)
#pragma unroll
            for (int mt = 0; mt < 4; mt++) {
                sacc[g][mt] = (floatx4){0.f, 0.f, 0.f, 0.f};
#pragma unroll
                for (int s = 0; s < 4; s++)
                    sacc[g][mt] = __builtin_amdgcn_mfma_f32_16x16x32_bf16(bcur[g][s], af[mt][s], sacc[g][mt], 0, 0, 0);
            }
        if (jt < 7) {                             // reload B frags for next tile
            const bf16_t* bn0 = Brow0 + (size_t)(jt + 1) * 128 * PCH;
            const bf16_t* bn1 = Brow1 + (size_t)(jt + 1) * 128 * PCH;
#pragma unroll
            for (int s = 0; s < 4; s++) {
                bcur[0][s] = *(const bf16x8*)&bn0[s * 32 + q * 8];
                bcur[1][s] = *(const bf16x8*)&bn1[s * 32 + q * 8];
            }
        }

        // ---- exp * 1/zsum -> Es[cur][i][j] (b64 per (g,mt): 4 consecutive j)
#pragma unroll
        for (int g = 0; g < 2; g++) {
            const float* wrp = g ? (const float*)&wr1 : (const float*)&wr0;
#pragma unroll
            for (int mt = 0; mt < 4; mt++) {
                bf16x4 ev;
#pragma unroll
                for (int r = 0; r < 4; r++)
                    ev[r] = (bf16_t)(__expf(sacc[g][mt][r] * SCALEF) * wrp[r]);
                *(bf16x4*)&Es[cur][(mt * 16 + tx) * LDJ2 + w * 32 + g * 16 + q * 4] = ev;
            }
        }
        float4 wn0, wn1;
        if (jt < 7) {                             // prefetch next wsum quads
            wn0 = *(const float4*)&wsum[j0 + 128 + w * 32 + q * 4];
            wn1 = *(const float4*)&wsum[j0 + 128 + w * 32 + 16 + q * 4];
        }

        __syncthreads();                          // Es[cur] visible; prev readers done

        // ---- GEMM2: out[i][d], K = this 128-j tile (per-s to limit ef liveness)
#pragma unroll
        for (int s = 0; s < 4; s++) {
            bf16x8 efs[4];
#pragma unroll
            for (int mt = 0; mt < 4; mt++)
                efs[mt] = *(bf16x8*)&Es[cur][(mt * 16 + tx) * LDJ2 + s * 32 + q * 8];
#pragma unroll
            for (int nt = 0; nt < 2; nt++)
#pragma unroll
                for (int mt = 0; mt < 4; mt++)
                    outacc[mt][nt] = __builtin_amdgcn_mfma_f32_16x16x32_bf16(efs[mt], vcur[nt][s], outacc[mt][nt], 0, 0, 0);
        }

        if (jt < 7) {                             // reload V frags + finish wsum rcp
#pragma unroll
            for (int nt = 0; nt < 2; nt++)
#pragma unroll
                for (int s = 0; s < 4; s++)
                    vcur[nt][s] = *(const bf16x8*)&Vc[((size_t)(w * 32 + nt * 16 + tx)) * NTOK + (j0 + 128) + s * 32 + q * 8];
            wr0 = (float4){1.f / wn0.x, 1.f / wn0.y, 1.f / wn0.z, 1.f / wn0.w};
            wr1 = (float4){1.f / wn1.x, 1.f / wn1.y, 1.f / wn1.z, 1.f / wn1.w};
        }
    }

    // ---- epilogue: accumulate j-quarter partial into fus
    float* fo = fus + ((size_t)(b * NTOK + i0)) * 256 + mode * 128 + w * 32;
#pragma unroll
    for (int mt = 0; mt < 4; mt++)
#pragma unroll
        for (int nt = 0; nt < 2; nt++)
#pragma unroll
            for (int r = 0; r < 4; r++)
                atomicAdd(&fo[(mt * 16 + q * 4 + r) * 256 + nt * 16 + tx], outacc[mt][nt][r]);
}

// ---------------------------------------------------------------------------
// K4: 1x1 conv (256 -> 128) + BN(eval) + ReLU.
// ---------------------------------------------------------------------------
__global__ __launch_bounds__(256) void conv_kernel(const float* __restrict__ fus,
                                                   const float* __restrict__ cw,
                                                   const float* __restrict__ cb,
                                                   const float* __restrict__ g,
                                                   const float* __restrict__ be,
                                                   const float* __restrict__ mu,
                                                   const float* __restrict__ var,
                                                   float* __restrict__ out)
{
    __shared__ float Ls[64][260];
    const int b = blockIdx.z, t = threadIdx.x;
    const int n0 = blockIdx.x * 64;
    const int obase = blockIdx.y * 32 + (t >> 6) * 8;   // wave-uniform

    const float4* src = (const float4*)(fus + ((size_t)(b * NTOK + n0)) * 256);
#pragma unroll
    for (int it = 0; it < 16; it++) {
        int row = it * 4 + (t >> 6);
        float4 v = src[row * 64 + (t & 63)];
        *(float4*)&Ls[row][(t & 63) * 4] = v;
    }
    __syncthreads();

    const int n = t & 63;
    float acc[8] = {};
    for (int c = 0; c < 256; c += 4) {
        float4 v = *(const float4*)&Ls[n][c];
#pragma unroll
        for (int oo = 0; oo < 8; oo++) {
            float4 wv = *(const float4*)&cw[(obase + oo) * 256 + c];
            acc[oo] += wv.x * v.x + wv.y * v.y + wv.z * v.z + wv.w * v.w;
        }
    }
#pragma unroll
    for (int oo = 0; oo < 8; oo++) {
        const int o = obase + oo;
        const float s  = g[o] * rsqrtf(var[o] + 1e-5f);
        const float b0 = be[o] + (cb[o] - mu[o]) * s;
        float y = acc[oo] * s + b0;
        out[((size_t)(b * OCH + o)) * NTOK + n0 + n] = fmaxf(y, 0.f);
    }
}

// ---------------------------------------------------------------------------
extern "C" void kernel_launch(void* const* d_in, const int* in_sizes, int n_in,
                              void* d_out, int out_size, void* d_ws, size_t ws_size,
                              hipStream_t stream)
{
    const float* pf   = (const float*)d_in[0];
    const float* img  = (const float*)d_in[1];
    const float* fc2w = (const float*)d_in[2];
    const float* fc2b = (const float*)d_in[3];
    const float* cw   = (const float*)d_in[4];
    const float* cb   = (const float*)d_in[5];
    const float* g    = (const float*)d_in[6];
    const float* be   = (const float*)d_in[7];
    const float* mu   = (const float*)d_in[8];
    const float* var  = (const float*)d_in[9];
    float* out = (float*)d_out;

    // ws layout: EXACTLY the proven footprint (16,842,752 B).
    float* fus   = (float*)d_ws;                              // 8 MB
    float* zrsum = fus + (size_t)NB * NTOK * 256;             // 32 KB
    float* zcsum = zrsum + NB * NTOK;                         // 32 KB
    bf16_t* pfC = (bf16_t*)(zcsum + NB * NTOK);               // 2 MB
    bf16_t* pfT = pfC + (size_t)NB * PCH * NTOK;              // 2 MB
    bf16_t* riC = pfT + (size_t)NB * NTOK * PCH;              // 2 MB
    bf16_t* riT = riC + (size_t)NB * PCH * NTOK;              // 2 MB

    // zero fus + zsums: (2*4096*256 + 2*2*4096) floats = 528384 float4
    zero_kernel<<<dim3(2064), 256, 0, stream>>>((float4*)d_ws);
    pack_pf    <<<dim3(64, 2, NB),  256, 0, stream>>>(pf, pfC, pfT);
    fc2_kernel <<<dim3(64, 4, NB),  256, 0, stream>>>(img, fc2w, fc2b, riC, riT);
    stats_mfma <<<dim3(64, NB, 4),  256, 0, stream>>>(pfT, riT, zrsum, zcsum);
    attn_mfma  <<<dim3(64, NB, 8),  256, 0, stream>>>(pfT, riT, pfC, riC, zrsum, zcsum, fus);
    conv_kernel<<<dim3(64, 4, NB),  256, 0, stream>>>(fus, cw, cb, g, be, mu, var, out);
}

// Round 10
// 249.329 us; speedup vs baseline: 1.2618x; 1.2618x over previous
//
#include <hip/hip_runtime.h>
#include <math.h>

// Problem constants
#define NTOK 4096
#define PCH  128
#define ICH  256
#define OCH  128
#define NB   2
#define SCALEF 0.08838834764831845f   // 1/sqrt(128)

typedef __bf16 bf16_t;
typedef __attribute__((ext_vector_type(8))) __bf16 bf16x8;
typedef __attribute__((ext_vector_type(4))) __bf16 bf16x4;
typedef __attribute__((ext_vector_type(4))) float floatx4;

#define LDK 136   // padded row length (bf16) for k=128 tiles
#define LDJ 72    // padded row length (bf16) for j=64 Es tiles

// ---------------------------------------------------------------------------
// K-1: zero fus (8 MB) + zsum buffers (64 KB) — contiguous at ws start.
// ---------------------------------------------------------------------------
__global__ __launch_bounds__(256) void zero_kernel(float4* __restrict__ p)
{
    p[(size_t)blockIdx.x * 256 + threadIdx.x] = float4{0.f, 0.f, 0.f, 0.f};
}

// ---------------------------------------------------------------------------
// K0: pack pf -> pfC (bf16 channel-major) + pfT (bf16 token-major)
// ---------------------------------------------------------------------------
__global__ __launch_bounds__(256) void pack_pf(const float* __restrict__ pf,
                                               bf16_t* __restrict__ pfC,
                                               bf16_t* __restrict__ pfT)
{
    __shared__ float Ls[64][65];
    const int t = threadIdx.x;
    const int n0 = blockIdx.x * 64, d0 = blockIdx.y * 64, b = blockIdx.z;
    const float* src = pf + ((size_t)(b * PCH + d0)) * NTOK + n0;
#pragma unroll
    for (int p = 0; p < 4; p++) {
        int d = p * 16 + (t >> 4), c = t & 15;
        float4 v = *(const float4*)&src[d * NTOK + c * 4];
        Ls[d][c * 4 + 0] = v.x; Ls[d][c * 4 + 1] = v.y;
        Ls[d][c * 4 + 2] = v.z; Ls[d][c * 4 + 3] = v.w;
        bf16x4 o = { (bf16_t)v.x, (bf16_t)v.y, (bf16_t)v.z, (bf16_t)v.w };
        *(bf16x4*)&pfC[((size_t)(b * PCH + d0 + d)) * NTOK + n0 + c * 4] = o;
    }
    __syncthreads();
#pragma unroll
    for (int p = 0; p < 2; p++) {
        int n = p * 32 + (t >> 3), c = t & 7;
        bf16x8 o;
#pragma unroll
        for (int k = 0; k < 8; k++) o[k] = (bf16_t)Ls[c * 8 + k][n];
        *(bf16x8*)&pfT[((size_t)(b * NTOK + n0 + n)) * PCH + d0 + c * 8] = o;
    }
}

// ---------------------------------------------------------------------------
// K1: fc2 — ri[b][p][n] = sum_c img[b][c][n]*w[p][c] + bias[p]
// ---------------------------------------------------------------------------
__global__ __launch_bounds__(256) void fc2_kernel(const float* __restrict__ img,
                                                  const float* __restrict__ w,
                                                  const float* __restrict__ bias,
                                                  bf16_t* __restrict__ riC,
                                                  bf16_t* __restrict__ riT)
{
    const int b = blockIdx.z, t = threadIdx.x;
    const int n = blockIdx.x * 64 + (t & 63);
    const int pbase = blockIdx.y * 32 + (t >> 6) * 8;   // wave-uniform
    const float* imgb = img + (size_t)b * ICH * NTOK + n;

    float acc[8];
#pragma unroll
    for (int pp = 0; pp < 8; pp++) acc[pp] = bias[pbase + pp];

    for (int c = 0; c < ICH; c += 4) {
        float v0 = imgb[(c + 0) * NTOK];
        float v1 = imgb[(c + 1) * NTOK];
        float v2 = imgb[(c + 2) * NTOK];
        float v3 = imgb[(c + 3) * NTOK];
#pragma unroll
        for (int pp = 0; pp < 8; pp++) {
            float4 wv = *(const float4*)&w[(pbase + pp) * ICH + c];
            acc[pp] += wv.x * v0 + wv.y * v1 + wv.z * v2 + wv.w * v3;
        }
    }

#pragma unroll
    for (int pp = 0; pp < 8; pp++)
        riC[((size_t)(b * PCH + pbase + pp)) * NTOK + n] = (bf16_t)acc[pp];
    bf16x8 tv;
#pragma unroll
    for (int pp = 0; pp < 8; pp++) tv[pp] = (bf16_t)acc[pp];
    *(bf16x8*)&riT[((size_t)(b * NTOK + n)) * PCH + pbase] = tv;
}

// ---------------------------------------------------------------------------
// K2: stats v5 (kept from R9 — ~50 us win vs v4) — one pass over
// E = exp(scale * pf_i . ri_j), both reductions:
//   zr[i] += sum_j E[i,j],  zc[j] += sum_i E[i,j]
// Direct-global B fragments + raw s_barrier pacing; zcol via LDS accumulator.
// ---------------------------------------------------------------------------
__global__ __launch_bounds__(256, 4) void stats_mfma(const bf16_t* __restrict__ pfT,
                                                     const bf16_t* __restrict__ riT,
                                                     float* __restrict__ zr,
                                                     float* __restrict__ zc)
{
    __shared__ bf16_t As[64 * LDK];
    __shared__ float zacc[1024];
    const int b = blockIdx.y, t = threadIdx.x;
    const int js = blockIdx.z;
    const bf16_t* At = pfT + (size_t)b * NTOK * PCH;
    const bf16_t* Bt = riT + (size_t)b * NTOK * PCH;
    float* zrow = zr + (size_t)b * NTOK;
    float* zcol = zc + (size_t)b * NTOK;
    const int lane = t & 63, w = t >> 6, tx = lane & 15, q = lane >> 4;
    const int i0 = blockIdx.x * 64;
    const int jbase = js * 1024;
    const int sr = t >> 4, sc = t & 15;
    const bf16_t* Brow = Bt + (size_t)(jbase + w * 16 + tx) * PCH;

    bf16x8 bcur[4];
#pragma unroll
    for (int s = 0; s < 4; s++)
        bcur[s] = *(const bf16x8*)&Brow[s * 32 + q * 8];
#pragma unroll
    for (int p = 0; p < 4; p++) {
        int i = p * 16 + sr;
        *(uint4*)&As[i * LDK + sc * 8] = *(const uint4*)&At[((size_t)(i0 + i)) * PCH + sc * 8];
    }
    __syncthreads();
    bf16x8 af[4][4];
#pragma unroll
    for (int mt = 0; mt < 4; mt++)
#pragma unroll
        for (int s = 0; s < 4; s++)
            af[mt][s] = *(bf16x8*)&As[(mt * 16 + tx) * LDK + s * 32 + q * 8];

    float racc[4] = {0.f, 0.f, 0.f, 0.f};
    for (int jt = 0; jt < 16; jt++) {
        __builtin_amdgcn_s_barrier();            // pacing only
        floatx4 sacc[4];
#pragma unroll
        for (int mt = 0; mt < 4; mt++) {
            sacc[mt] = (floatx4){0.f, 0.f, 0.f, 0.f};
#pragma unroll
            for (int s = 0; s < 4; s++)
                sacc[mt] = __builtin_amdgcn_mfma_f32_16x16x32_bf16(bcur[s], af[mt][s], sacc[mt], 0, 0, 0);
        }
        if (jt < 15) {
            const bf16_t* bn = Brow + (size_t)(jt + 1) * 64 * PCH;
#pragma unroll
            for (int s = 0; s < 4; s++)
                bcur[s] = *(const bf16x8*)&bn[s * 32 + q * 8];
        }

        float ctmp[4] = {0.f, 0.f, 0.f, 0.f};
#pragma unroll
        for (int mt = 0; mt < 4; mt++)
#pragma unroll
            for (int r = 0; r < 4; r++) {
                float e = __expf(sacc[mt][r] * SCALEF);
                racc[mt] += e;
                ctmp[r]  += e;
            }
#pragma unroll
        for (int r = 0; r < 4; r++) {
            float v = ctmp[r];
            v += __shfl_xor(v, 1); v += __shfl_xor(v, 2);
            v += __shfl_xor(v, 4); v += __shfl_xor(v, 8);
            if (tx == 0) zacc[jt * 64 + w * 16 + q * 4 + r] = v;
        }
    }
#pragma unroll
    for (int mt = 0; mt < 4; mt++) {
        float v = racc[mt];
        v += __shfl_xor(v, 16);
        v += __shfl_xor(v, 32);
        if (q == 0) atomicAdd(&zrow[i0 + mt * 16 + tx], v);
    }
    __syncthreads();
#pragma unroll
    for (int k = 0; k < 4; k++)
        atomicAdd(&zcol[jbase + k * 256 + t], zacc[k * 256 + t]);
}

// ---------------------------------------------------------------------------
// K3: attn (REVERTED to R8's proven 81us version — R9's 128-j tile spilled
// to scratch: VGPR stayed 84 with 2x live state -> FETCH 34->205MB, WRITE
// 32->94MB. Keep 64-j tile; register budget fits).
// ---------------------------------------------------------------------------
__global__ __launch_bounds__(256, 3) void attn_mfma(const bf16_t* __restrict__ pfT,
                                                    const bf16_t* __restrict__ riT,
                                                    const bf16_t* __restrict__ pfC,
                                                    const bf16_t* __restrict__ riC,
                                                    const float* __restrict__ zrsum,
                                                    const float* __restrict__ zcsum,
                                                    float* __restrict__ fus)
{
    __shared__ bf16_t As[64 * LDK];
    __shared__ bf16_t Es[2][64 * LDJ];
    const int b = blockIdx.y, t = threadIdx.x;
    const int mode = blockIdx.z >> 2, js = blockIdx.z & 3;
    const bf16_t* At = (mode == 0 ? pfT : riT) + (size_t)b * NTOK * PCH;
    const bf16_t* Bt = (mode == 0 ? riT : pfT) + (size_t)b * NTOK * PCH;
    const bf16_t* Vc = (mode == 0 ? pfC : riC) + (size_t)b * PCH * NTOK;
    const float* wsum = (mode == 0 ? zcsum : zrsum) + (size_t)b * NTOK;
    const int lane = t & 63, w = t >> 6, tx = lane & 15, q = lane >> 4;
    const int i0 = blockIdx.x * 64;
    const int jbase = js * 1024;
    const int sr = t >> 4, sc = t & 15;
    const bf16_t* Brow = Bt + (size_t)(jbase + w * 16 + tx) * PCH;

    bf16x8 bcur[4];
#pragma unroll
    for (int s = 0; s < 4; s++)
        bcur[s] = *(const bf16x8*)&Brow[s * 32 + q * 8];
    bf16x8 vcur[2][2];
#pragma unroll
    for (int nt = 0; nt < 2; nt++)
#pragma unroll
        for (int s = 0; s < 2; s++)
            vcur[nt][s] = *(const bf16x8*)&Vc[((size_t)(w * 32 + nt * 16 + tx)) * NTOK + jbase + s * 32 + q * 8];
    float4 wv = *(const float4*)&wsum[jbase + w * 16 + q * 4];
    float4 wr4 = {1.f / wv.x, 1.f / wv.y, 1.f / wv.z, 1.f / wv.w};

#pragma unroll
    for (int p = 0; p < 4; p++) {
        int i = p * 16 + sr;
        *(uint4*)&As[i * LDK + sc * 8] = *(const uint4*)&At[((size_t)(i0 + i)) * PCH + sc * 8];
    }
    __syncthreads();
    bf16x8 af[4][4];
#pragma unroll
    for (int mt = 0; mt < 4; mt++)
#pragma unroll
        for (int s = 0; s < 4; s++)
            af[mt][s] = *(bf16x8*)&As[(mt * 16 + tx) * LDK + s * 32 + q * 8];

    floatx4 outacc[4][2];
#pragma unroll
    for (int mt = 0; mt < 4; mt++)
#pragma unroll
        for (int nt = 0; nt < 2; nt++)
            outacc[mt][nt] = (floatx4){0.f, 0.f, 0.f, 0.f};

    for (int jt = 0; jt < 16; jt++) {
        const int cur = jt & 1;
        const int j0 = jbase + jt * 64;

        floatx4 sacc[4];
#pragma unroll
        for (int mt = 0; mt < 4; mt++) {
            sacc[mt] = (floatx4){0.f, 0.f, 0.f, 0.f};
#pragma unroll
            for (int s = 0; s < 4; s++)
                sacc[mt] = __builtin_amdgcn_mfma_f32_16x16x32_bf16(bcur[s], af[mt][s], sacc[mt], 0, 0, 0);
        }
        if (jt < 15) {
            const bf16_t* bn = Brow + (size_t)(jt + 1) * 64 * PCH;
#pragma unroll
            for (int s = 0; s < 4; s++)
                bcur[s] = *(const bf16x8*)&bn[s * 32 + q * 8];
        }

#pragma unroll
        for (int mt = 0; mt < 4; mt++) {
            bf16x4 ev;
#pragma unroll
            for (int r = 0; r < 4; r++)
                ev[r] = (bf16_t)(__expf(sacc[mt][r] * SCALEF) * ((const float*)&wr4)[r]);
            *(bf16x4*)&Es[cur][(mt * 16 + tx) * LDJ + w * 16 + q * 4] = ev;
        }
        float4 wnv;
        if (jt < 15)
            wnv = *(const float4*)&wsum[j0 + 64 + w * 16 + q * 4];

        __syncthreads();

        bf16x8 ef[4][2];
#pragma unroll
        for (int mt = 0; mt < 4; mt++)
#pragma unroll
            for (int s = 0; s < 2; s++)
                ef[mt][s] = *(bf16x8*)&Es[cur][(mt * 16 + tx) * LDJ + s * 32 + q * 8];
#pragma unroll
        for (int nt = 0; nt < 2; nt++)
#pragma unroll
            for (int s = 0; s < 2; s++)
#pragma unroll
                for (int mt = 0; mt < 4; mt++)
                    outacc[mt][nt] = __builtin_amdgcn_mfma_f32_16x16x32_bf16(ef[mt][s], vcur[nt][s], outacc[mt][nt], 0, 0, 0);

        if (jt < 15) {
#pragma unroll
            for (int nt = 0; nt < 2; nt++)
#pragma unroll
                for (int s = 0; s < 2; s++)
                    vcur[nt][s] = *(const bf16x8*)&Vc[((size_t)(w * 32 + nt * 16 + tx)) * NTOK + (j0 + 64) + s * 32 + q * 8];
            wr4 = (float4){1.f / wnv.x, 1.f / wnv.y, 1.f / wnv.z, 1.f / wnv.w};
        }
    }

    float* fo = fus + ((size_t)(b * NTOK + i0)) * 256 + mode * 128 + w * 32;
#pragma unroll
    for (int mt = 0; mt < 4; mt++)
#pragma unroll
        for (int nt = 0; nt < 2; nt++)
#pragma unroll
            for (int r = 0; r < 4; r++)
                atomicAdd(&fo[(mt * 16 + q * 4 + r) * 256 + nt * 16 + tx], outacc[mt][nt][r]);
}

// ---------------------------------------------------------------------------
// K4: 1x1 conv (256 -> 128) + BN(eval) + ReLU.
// ---------------------------------------------------------------------------
__global__ __launch_bounds__(256) void conv_kernel(const float* __restrict__ fus,
                                                   const float* __restrict__ cw,
                                                   const float* __restrict__ cb,
                                                   const float* __restrict__ g,
                                                   const float* __restrict__ be,
                                                   const float* __restrict__ mu,
                                                   const float* __restrict__ var,
                                                   float* __restrict__ out)
{
    __shared__ float Ls[64][260];
    const int b = blockIdx.z, t = threadIdx.x;
    const int n0 = blockIdx.x * 64;
    const int obase = blockIdx.y * 32 + (t >> 6) * 8;   // wave-uniform

    const float4* src = (const float4*)(fus + ((size_t)(b * NTOK + n0)) * 256);
#pragma unroll
    for (int it = 0; it < 16; it++) {
        int row = it * 4 + (t >> 6);
        float4 v = src[row * 64 + (t & 63)];
        *(float4*)&Ls[row][(t & 63) * 4] = v;
    }
    __syncthreads();

    const int n = t & 63;
    float acc[8] = {};
    for (int c = 0; c < 256; c += 4) {
        float4 v = *(const float4*)&Ls[n][c];
#pragma unroll
        for (int oo = 0; oo < 8; oo++) {
            float4 wv = *(const float4*)&cw[(obase + oo) * 256 + c];
            acc[oo] += wv.x * v.x + wv.y * v.y + wv.z * v.z + wv.w * v.w;
        }
    }
#pragma unroll
    for (int oo = 0; oo < 8; oo++) {
        const int o = obase + oo;
        const float s  = g[o] * rsqrtf(var[o] + 1e-5f);
        const float b0 = be[o] + (cb[o] - mu[o]) * s;
        float y = acc[oo] * s + b0;
        out[((size_t)(b * OCH + o)) * NTOK + n0 + n] = fmaxf(y, 0.f);
    }
}

// ---------------------------------------------------------------------------
extern "C" void kernel_launch(void* const* d_in, const int* in_sizes, int n_in,
                              void* d_out, int out_size, void* d_ws, size_t ws_size,
                              hipStream_t stream)
{
    const float* pf   = (const float*)d_in[0];
    const float* img  = (const float*)d_in[1];
    const float* fc2w = (const float*)d_in[2];
    const float* fc2b = (const float*)d_in[3];
    const float* cw   = (const float*)d_in[4];
    const float* cb   = (const float*)d_in[5];
    const float* g    = (const float*)d_in[6];
    const float* be   = (const float*)d_in[7];
    const float* mu   = (const float*)d_in[8];
    const float* var  = (const float*)d_in[9];
    float* out = (float*)d_out;

    // ws layout: EXACTLY the proven footprint (16,842,752 B).
    float* fus   = (float*)d_ws;                              // 8 MB
    float* zrsum = fus + (size_t)NB * NTOK * 256;             // 32 KB
    float* zcsum = zrsum + NB * NTOK;                         // 32 KB
    bf16_t* pfC = (bf16_t*)(zcsum + NB * NTOK);               // 2 MB
    bf16_t* pfT = pfC + (size_t)NB * PCH * NTOK;              // 2 MB
    bf16_t* riC = pfT + (size_t)NB * NTOK * PCH;              // 2 MB
    bf16_t* riT = riC + (size_t)NB * PCH * NTOK;              // 2 MB

    // zero fus + zsums: (2*4096*256 + 2*2*4096) floats = 528384 float4
    zero_kernel<<<dim3(2064), 256, 0, stream>>>((float4*)d_ws);
    pack_pf    <<<dim3(64, 2, NB),  256, 0, stream>>>(pf, pfC, pfT);
    fc2_kernel <<<dim3(64, 4, NB),  256, 0, stream>>>(img, fc2w, fc2b, riC, riT);
    stats_mfma <<<dim3(64, NB, 4),  256, 0, stream>>>(pfT, riT, zrsum, zcsum);
    attn_mfma  <<<dim3(64, NB, 8),  256, 0, stream>>>(pfT, riT, pfC, riC, zrsum, zcsum, fus);
    conv_kernel<<<dim3(64, 4, NB),  256, 0, stream>>>(fus, cw, cb, g, be, mu, var, out);
}